// Round 6
// baseline (460.181 us; speedup 1.0000x reference)
//
#include <hip/hip_runtime.h>
#include <hip/hip_bf16.h>

#define H 4
#define NS 8192
#define NT 4096
#define DIN 128
#define DOUT 64
#define ROW_CAP 1024   // 16*64
#define COL_CAP 512    // 8*64
#define NEGBIG -3.0e38f

typedef unsigned short ushort8_t __attribute__((ext_vector_type(8)));

__device__ __forceinline__ float lrelu(float x) { return x >= 0.f ? x : 0.1f * x; }
__device__ __forceinline__ float eluf(float x) { return x > 0.f ? x : expm1f(x); }

__device__ __forceinline__ float waveMax(float v) {
    for (int off = 32; off > 0; off >>= 1) v = fmaxf(v, __shfl_xor(v, off, 64));
    return v;
}
__device__ __forceinline__ float waveSum(float v) {
    for (int off = 32; off > 0; off >>= 1) v += __shfl_xor(v, off, 64);
    return v;
}
// broadcast lane `l` (runtime wave-uniform) of v to all lanes via v_readlane -> SGPR
__device__ __forceinline__ float rlane(float v, int l) {
    return __int_as_float(__builtin_amdgcn_readlane(__float_as_int(v), l));
}

// ---------------------------------------------------------------------------
// Projection: Hout[h,s,o] = sum_i X[s,i] * W[h,i,o];  b[h,s] = Hout[h,s,:]·a[h,:]
// grid (N/16, H), block 256.
// ---------------------------------------------------------------------------
__global__ __launch_bounds__(256) void proj_kernel(
    const float* __restrict__ X, const float* __restrict__ W,
    const float* __restrict__ a_vec, float* __restrict__ Hout,
    float* __restrict__ b_out, int N) {
    __shared__ float w_lds[DIN * DOUT];   // 32 KB
    __shared__ float a_lds[16 * 129];
    const int h = blockIdx.y;
    const int row0 = blockIdx.x * 16;
    const int tid = threadIdx.x;

    const float* Wh = W + (size_t)h * DIN * DOUT;
    for (int i = tid; i < DIN * DOUT; i += 256) w_lds[i] = Wh[i];
    for (int i = tid; i < 16 * DIN; i += 256) {
        int r = i >> 7, c = i & 127;
        a_lds[r * 129 + c] = X[(size_t)(row0 + r) * DIN + c];
    }
    __syncthreads();

    const int fg = (tid & 15) * 4;
    const int r = tid >> 4;
    const float* ar = &a_lds[r * 129];
    float acc0 = 0.f, acc1 = 0.f, acc2 = 0.f, acc3 = 0.f;
#pragma unroll 8
    for (int i = 0; i < DIN; ++i) {
        float av = ar[i];
        float4 wv = *reinterpret_cast<const float4*>(&w_lds[i * DOUT + fg]);
        acc0 += av * wv.x; acc1 += av * wv.y; acc2 += av * wv.z; acc3 += av * wv.w;
    }
    const int s = row0 + r;
    float4 o = make_float4(acc0, acc1, acc2, acc3);
    *reinterpret_cast<float4*>(&Hout[((size_t)h * N + s) * DOUT + fg]) = o;

    const float* av = a_vec + h * DOUT + fg;
    float part = acc0 * av[0] + acc1 * av[1] + acc2 * av[2] + acc3 * av[3];
    for (int off = 8; off > 0; off >>= 1) part += __shfl_xor(part, off, 64);
    if ((tid & 15) == 0) b_out[(size_t)h * N + s] = part;
}

// ---------------------------------------------------------------------------
// Mask build: one HBM pass over dense A -> row-major + col-major bitmasks.
// ---------------------------------------------------------------------------
__global__ __launch_bounds__(256) void mask_kernel(
    const float* __restrict__ A,
    unsigned long long* __restrict__ mask_row,
    unsigned long long* __restrict__ mask_col) {
    __shared__ unsigned long long rowbits[64];
    const int s0 = blockIdx.x * 64;
    const int t0 = blockIdx.y * 64;
    const int lane = threadIdx.x & 63;
    const int w = threadIdx.x >> 6;
    for (int rr = w; rr < 64; rr += 4) {
        const int t = t0 + rr;
        float v = A[(size_t)t * NS + s0 + lane];
        unsigned long long word = __ballot(v != 0.0f);
        if (lane == 0) {
            mask_row[(size_t)t * (NS / 64) + (s0 >> 6)] = word;
            rowbits[rr] = word;
        }
    }
    __syncthreads();
    if (threadIdx.x < 64) {
        const int j = threadIdx.x;
        unsigned long long cw = 0;
        for (int rr = 0; rr < 64; ++rr) cw |= ((rowbits[rr] >> j) & 1ull) << rr;
        mask_col[(size_t)(s0 + j) * (NT / 64) + (t0 >> 6)] = cw;
    }
}

// ---------------------------------------------------------------------------
// Compaction: bitmask words -> index list via __shfl_up wave scan.
// ---------------------------------------------------------------------------
template <int NW, int CAP>
__device__ __forceinline__ int compact_list(
    const unsigned long long* __restrict__ mask, size_t mask_row_off,
    unsigned short* list, int* wtot, int tid) {
    unsigned long long word = 0;
    int c = 0;
    if (tid < NW) {
        word = mask[mask_row_off + tid];
        c = __popcll(word);
    }
    int incl = c;
#pragma unroll
    for (int d = 1; d < 64; d <<= 1) {
        int v = __shfl_up(incl, d, 64);
        if ((tid & 63) >= d) incl += v;
    }
    if ((tid & 63) == 63) wtot[tid >> 6] = incl;
    __syncthreads();
    int base_off = 0;
#pragma unroll
    for (int wv = 0; wv < (NW / 64); ++wv) {
        int v = wtot[wv];
        if (wv < (tid >> 6)) base_off += v;
    }
    int nnz = 0;
#pragma unroll
    for (int wv = 0; wv < (NW / 64); ++wv) nnz += wtot[wv];
    if (tid < NW) {
        int off = base_off + incl - c;
        unsigned long long wd = word;
        const int base = tid * 64;
        while (wd) {
            int b = __ffsll((long long)wd) - 1;
            if (off < CAP) list[off] = (unsigned short)(base + b);
            ++off;
            wd &= wd - 1;
        }
    }
    nnz = nnz > CAP ? CAP : nnz;
    // zero-pad list up to the next multiple of 64 (pad weights will be 0)
    int nk64 = (nnz + 63) & ~63;
    for (int j = nnz + tid; j < nk64; j += 256) list[j] = 0;
    return nnz;
}

// ---------------------------------------------------------------------------
// Core per-(h,row) attention: weights kept in registers wreg[KMAX]
// (j's weight lives in lane j&63, slot j>>6). Gather broadcasts via readlane.
// ---------------------------------------------------------------------------
template <int KMAX>
__device__ __forceinline__ float attn_core(
    const unsigned short* __restrict__ list, int nnz,
    const float* __restrict__ bvec,   // bs (row dir) or bt (col dir), head slice
    float bias,                       // btv / bsv
    const float* __restrict__ src,    // hs/ht head slice, wave-uniform base
    int lane) {
    const int nk = (nnz + 63) >> 6;
    float wreg[KMAX];

    // pass 1: gather partner biases, find max
    float m = NEGBIG;
#pragma unroll
    for (int k = 0; k < KMAX; ++k) {
        if (k >= nk) break;
        int j = (k << 6) + lane;
        float p = NEGBIG;
        if (j < nnz) p = bvec[list[j]];
        wreg[k] = p;
        m = fmaxf(m, p);
    }
    m = waveMax(m);
    const float mrow = lrelu(bias + m);   // lrelu monotone => exact max

    // pass 2: weights into registers (0 for pads), sum
    float ssum = 0.f;
#pragma unroll
    for (int k = 0; k < KMAX; ++k) {
        if (k >= nk) break;
        int j = (k << 6) + lane;
        float w = 0.f;
        if (j < nnz) w = __expf(lrelu(bias + wreg[k]) - mrow);
        wreg[k] = w;
        ssum += w;
    }
    ssum = waveSum(ssum);
    const float rs = ssum > 0.f ? 1.0f / ssum : 0.f;

    // gather: per k, 64 j's; idx via wave-uniform b128 LDS reads (broadcast),
    // weight via v_readlane (SGPR), 8 loads in flight.
    const char* basec = (const char*)src;
    const unsigned laneByte = (unsigned)lane << 2;
    float a0 = 0.f, a1 = 0.f, a2 = 0.f, a3 = 0.f;
    float a4 = 0.f, a5 = 0.f, a6 = 0.f, a7 = 0.f;
#pragma unroll
    for (int k = 0; k < KMAX; ++k) {
        if (k >= nk) break;
        const float wk = wreg[k];
        const ushort8_t* lp = reinterpret_cast<const ushort8_t*>(&list[k << 6]);
        for (int g = 0; g < 8; ++g) {
            ushort8_t ix = lp[g];
            const int l = g << 3;
            a0 += rlane(wk, l + 0) * *(const float*)(basec + (((unsigned)ix[0]) << 8) + laneByte);
            a1 += rlane(wk, l + 1) * *(const float*)(basec + (((unsigned)ix[1]) << 8) + laneByte);
            a2 += rlane(wk, l + 2) * *(const float*)(basec + (((unsigned)ix[2]) << 8) + laneByte);
            a3 += rlane(wk, l + 3) * *(const float*)(basec + (((unsigned)ix[3]) << 8) + laneByte);
            a4 += rlane(wk, l + 4) * *(const float*)(basec + (((unsigned)ix[4]) << 8) + laneByte);
            a5 += rlane(wk, l + 5) * *(const float*)(basec + (((unsigned)ix[5]) << 8) + laneByte);
            a6 += rlane(wk, l + 6) * *(const float*)(basec + (((unsigned)ix[6]) << 8) + laneByte);
            a7 += rlane(wk, l + 7) * *(const float*)(basec + (((unsigned)ix[7]) << 8) + laneByte);
        }
    }
    float acc = ((a0 + a1) + (a2 + a3)) + ((a4 + a5) + (a6 + a7));
    return acc * rs;
}

// ---------------------------------------------------------------------------
// Row direction: softmax over sources s for each (h,t); h_ts = elu(attn @ hs).
// grid NT, block 256 (wave = head).
// ---------------------------------------------------------------------------
__global__ __launch_bounds__(256) void attn_row_kernel(
    const unsigned long long* __restrict__ mask_row,
    const float* __restrict__ bs, const float* __restrict__ bt,
    const float* __restrict__ hs, float* __restrict__ out_ts) {
    __shared__ __align__(16) unsigned short list[ROW_CAP];
    __shared__ int wtot[4];

    const int t = blockIdx.x;
    const int tid = threadIdx.x;
    const int nnz = compact_list<NS / 64, ROW_CAP>(
        mask_row, (size_t)t * (NS / 64), list, wtot, tid);
    __syncthreads();

    const int h = tid >> 6, lane = tid & 63;
    const float btv = bt[(size_t)h * NT + t];
    float r = attn_core<ROW_CAP / 64>(list, nnz, bs + (size_t)h * NS, btv,
                                      hs + (size_t)h * NS * DOUT, lane);
    out_ts[(size_t)t * (H * DOUT) + h * DOUT + lane] = eluf(r);
}

// ---------------------------------------------------------------------------
// Col direction: softmax over targets t for each (h,s); h_st = elu(attn^T @ ht).
// grid NS, block 256 (wave = head).
// ---------------------------------------------------------------------------
__global__ __launch_bounds__(256) void attn_col_kernel(
    const unsigned long long* __restrict__ mask_col,
    const float* __restrict__ bs, const float* __restrict__ bt,
    const float* __restrict__ ht, float* __restrict__ out_st) {
    __shared__ __align__(16) unsigned short list[COL_CAP];
    __shared__ int wtot[4];

    const int s = blockIdx.x;
    const int tid = threadIdx.x;
    const int nnz = compact_list<NT / 64, COL_CAP>(
        mask_col, (size_t)s * (NT / 64), list, wtot, tid);
    __syncthreads();

    const int h = tid >> 6, lane = tid & 63;
    const float bsv = bs[(size_t)h * NS + s];
    float r = attn_core<COL_CAP / 64>(list, nnz, bt + (size_t)h * NT, bsv,
                                      ht + (size_t)h * NT * DOUT, lane);
    out_st[(size_t)s * (H * DOUT) + h * DOUT + lane] = eluf(r);
}

// ---------------------------------------------------------------------------
extern "C" void kernel_launch(void* const* d_in, const int* in_sizes, int n_in,
                              void* d_out, int out_size, void* d_ws, size_t ws_size,
                              hipStream_t stream) {
    const float* input1 = (const float*)d_in[0];  // [8192,128]
    const float* input2 = (const float*)d_in[1];  // [4096,128]
    const float* A      = (const float*)d_in[2];  // [4096,8192]
    const float* Ws     = (const float*)d_in[3];  // [4,128,64]
    const float* Wt     = (const float*)d_in[4];  // [4,128,64]
    const float* a_src  = (const float*)d_in[5];  // [4,64]
    const float* a_tgt  = (const float*)d_in[6];  // [4,64]
    float* out = (float*)d_out;  // out_st [8192,256] then out_ts [4096,256]

    char* ws = (char*)d_ws;
    float* hs = (float*)(ws + 0);                              // 8 MB   [H,NS,64]
    float* ht = (float*)(ws + 8388608);                        // 4 MB   [H,NT,64]
    float* bs = (float*)(ws + 12582912);                       // 128 KB [H,NS]
    float* bt = (float*)(ws + 12713984);                       // 64 KB  [H,NT]
    unsigned long long* mask_row = (unsigned long long*)(ws + 12779520);  // 4 MB
    unsigned long long* mask_col = (unsigned long long*)(ws + 16973824);  // 4 MB

    proj_kernel<<<dim3(NS / 16, H), 256, 0, stream>>>(input1, Ws, a_src, hs, bs, NS);
    proj_kernel<<<dim3(NT / 16, H), 256, 0, stream>>>(input2, Wt, a_tgt, ht, bt, NT);
    mask_kernel<<<dim3(NS / 64, NT / 64), 256, 0, stream>>>(A, mask_row, mask_col);
    attn_row_kernel<<<NT, 256, 0, stream>>>(mask_row, bs, bt, hs,
                                            out + (size_t)NS * (H * DOUT));
    attn_col_kernel<<<NS, 256, 0, stream>>>(mask_col, bs, bt, ht, out);
}

// Round 8
// 428.439 us; speedup vs baseline: 1.0741x; 1.0741x over previous
//
#include <hip/hip_runtime.h>
#include <hip/hip_bf16.h>

#define H 4
#define NS 8192
#define NT 4096
#define DIN 128
#define DOUT 64
#define ROW_CAP 1024   // 16*64 per row
#define COL_CAP 512    // 8*64 per row
#define NEGBIG -3.0e38f

typedef unsigned short ushort8_t __attribute__((ext_vector_type(8)));

__device__ __forceinline__ float lrelu(float x) { return x >= 0.f ? x : 0.1f * x; }
__device__ __forceinline__ float eluf(float x) { return x > 0.f ? x : expm1f(x); }

__device__ __forceinline__ float waveMax(float v) {
    for (int off = 32; off > 0; off >>= 1) v = fmaxf(v, __shfl_xor(v, off, 64));
    return v;
}
__device__ __forceinline__ float waveSum(float v) {
    for (int off = 32; off > 0; off >>= 1) v += __shfl_xor(v, off, 64);
    return v;
}
// broadcast lane `l` (compile-time-unrolled) of v to all lanes via v_readlane -> SGPR
__device__ __forceinline__ float rlane(float v, int l) {
    return __int_as_float(__builtin_amdgcn_readlane(__float_as_int(v), l));
}

// ---------------------------------------------------------------------------
// Projection: Hout[h,s,o] = sum_i X[s,i] * W[h,i,o];  b[h,s] = Hout[h,s,:]·a[h,:]
// grid (N/16, H), block 256.
// ---------------------------------------------------------------------------
__global__ __launch_bounds__(256) void proj_kernel(
    const float* __restrict__ X, const float* __restrict__ W,
    const float* __restrict__ a_vec, float* __restrict__ Hout,
    float* __restrict__ b_out, int N) {
    __shared__ float w_lds[DIN * DOUT];   // 32 KB
    __shared__ float a_lds[16 * 129];
    const int h = blockIdx.y;
    const int row0 = blockIdx.x * 16;
    const int tid = threadIdx.x;

    const float* Wh = W + (size_t)h * DIN * DOUT;
    for (int i = tid; i < DIN * DOUT; i += 256) w_lds[i] = Wh[i];
    for (int i = tid; i < 16 * DIN; i += 256) {
        int r = i >> 7, c = i & 127;
        a_lds[r * 129 + c] = X[(size_t)(row0 + r) * DIN + c];
    }
    __syncthreads();

    const int fg = (tid & 15) * 4;
    const int r = tid >> 4;
    const float* ar = &a_lds[r * 129];
    float acc0 = 0.f, acc1 = 0.f, acc2 = 0.f, acc3 = 0.f;
#pragma unroll 8
    for (int i = 0; i < DIN; ++i) {
        float av = ar[i];
        float4 wv = *reinterpret_cast<const float4*>(&w_lds[i * DOUT + fg]);
        acc0 += av * wv.x; acc1 += av * wv.y; acc2 += av * wv.z; acc3 += av * wv.w;
    }
    const int s = row0 + r;
    float4 o = make_float4(acc0, acc1, acc2, acc3);
    *reinterpret_cast<float4*>(&Hout[((size_t)h * N + s) * DOUT + fg]) = o;

    const float* av = a_vec + h * DOUT + fg;
    float part = acc0 * av[0] + acc1 * av[1] + acc2 * av[2] + acc3 * av[3];
    for (int off = 8; off > 0; off >>= 1) part += __shfl_xor(part, off, 64);
    if ((tid & 15) == 0) b_out[(size_t)h * N + s] = part;
}

// ---------------------------------------------------------------------------
// Mask build: one HBM pass over dense A -> row-major + col-major bitmasks.
// ---------------------------------------------------------------------------
__global__ __launch_bounds__(256) void mask_kernel(
    const float* __restrict__ A,
    unsigned long long* __restrict__ mask_row,
    unsigned long long* __restrict__ mask_col) {
    __shared__ unsigned long long rowbits[64];
    const int s0 = blockIdx.x * 64;
    const int t0 = blockIdx.y * 64;
    const int lane = threadIdx.x & 63;
    const int w = threadIdx.x >> 6;
    for (int rr = w; rr < 64; rr += 4) {
        const int t = t0 + rr;
        float v = A[(size_t)t * NS + s0 + lane];
        unsigned long long word = __ballot(v != 0.0f);
        if (lane == 0) {
            mask_row[(size_t)t * (NS / 64) + (s0 >> 6)] = word;
            rowbits[rr] = word;
        }
    }
    __syncthreads();
    if (threadIdx.x < 64) {
        const int j = threadIdx.x;
        unsigned long long cw = 0;
        for (int rr = 0; rr < 64; ++rr) cw |= ((rowbits[rr] >> j) & 1ull) << rr;
        mask_col[(size_t)(s0 + j) * (NT / 64) + (t0 >> 6)] = cw;
    }
}

// ---------------------------------------------------------------------------
// Per-WAVE compaction: NWORDS bitmask words -> index list, wave-scan offsets.
// No cross-wave dependencies (no barriers needed).
// ---------------------------------------------------------------------------
template <int NWORDS, int CAP>
__device__ __forceinline__ int wave_compact(
    const unsigned long long* __restrict__ mask, size_t word_base,
    unsigned short* list, int lane) {
    int total = 0;
#pragma unroll
    for (int c = 0; c < NWORDS / 64; ++c) {
        unsigned long long wd = mask[word_base + c * 64 + lane];
        int cnt = __popcll(wd);
        int incl = cnt;
#pragma unroll
        for (int d = 1; d < 64; d <<= 1) {
            int v = __shfl_up(incl, d, 64);
            if (lane >= d) incl += v;
        }
        int off = total + incl - cnt;
        const int base = (c * 64 + lane) * 64;
        while (wd) {
            int b = __ffsll((long long)wd) - 1;
            if (off < CAP) list[off] = (unsigned short)(base + b);
            ++off;
            wd &= wd - 1;
        }
        total += __shfl(incl, 63, 64);
    }
    int nnz = total > CAP ? CAP : total;
    int nk64 = (nnz + 63) & ~63;
    for (int j = nnz + lane; j < nk64; j += 64) list[j] = 0;
    return nnz;
}

// ---------------------------------------------------------------------------
// Core per-(h,row) attention: weights in registers wreg[KMAX]
// (j's weight lives in lane j&63, slot j>>6). Gather broadcasts via readlane.
// ---------------------------------------------------------------------------
template <int KMAX>
__device__ __forceinline__ float attn_core(
    const unsigned short* __restrict__ list, int nnz,
    const float* __restrict__ bvec,   // partner bias vector, head slice
    float bias,                       // own bias
    const float* __restrict__ src,    // hs/ht head slice
    int lane) {
    const int nk = (nnz + 63) >> 6;
    float wreg[KMAX];

    // pass 1: gather partner biases, find max
    float m = NEGBIG;
#pragma unroll
    for (int k = 0; k < KMAX; ++k) {
        if (k >= nk) break;
        int j = (k << 6) + lane;
        float p = NEGBIG;
        if (j < nnz) p = bvec[list[j]];
        wreg[k] = p;
        m = fmaxf(m, p);
    }
    m = waveMax(m);
    const float mrow = lrelu(bias + m);   // lrelu monotone => exact max

    // pass 2: weights into registers (0 for pads), sum
    float ssum = 0.f;
#pragma unroll
    for (int k = 0; k < KMAX; ++k) {
        if (k >= nk) break;
        int j = (k << 6) + lane;
        float w = 0.f;
        if (j < nnz) w = __expf(lrelu(bias + wreg[k]) - mrow);
        wreg[k] = w;
        ssum += w;
    }
    ssum = waveSum(ssum);
    const float rs = ssum > 0.f ? 1.0f / ssum : 0.f;

    // gather: per k, 64 j's; idx via wave-uniform b128 LDS reads (broadcast),
    // weight via v_readlane (SGPR), 8 loads in flight.
    const char* basec = (const char*)src;
    const unsigned laneByte = (unsigned)lane << 2;
    float a0 = 0.f, a1 = 0.f, a2 = 0.f, a3 = 0.f;
    float a4 = 0.f, a5 = 0.f, a6 = 0.f, a7 = 0.f;
#pragma unroll
    for (int k = 0; k < KMAX; ++k) {
        if (k >= nk) break;
        const float wk = wreg[k];
        const ushort8_t* lp = reinterpret_cast<const ushort8_t*>(&list[k << 6]);
        for (int g = 0; g < 8; ++g) {
            ushort8_t ix = lp[g];
            const int l = g << 3;
            a0 += rlane(wk, l + 0) * *(const float*)(basec + (((unsigned)ix[0]) << 8) + laneByte);
            a1 += rlane(wk, l + 1) * *(const float*)(basec + (((unsigned)ix[1]) << 8) + laneByte);
            a2 += rlane(wk, l + 2) * *(const float*)(basec + (((unsigned)ix[2]) << 8) + laneByte);
            a3 += rlane(wk, l + 3) * *(const float*)(basec + (((unsigned)ix[3]) << 8) + laneByte);
            a4 += rlane(wk, l + 4) * *(const float*)(basec + (((unsigned)ix[4]) << 8) + laneByte);
            a5 += rlane(wk, l + 5) * *(const float*)(basec + (((unsigned)ix[5]) << 8) + laneByte);
            a6 += rlane(wk, l + 6) * *(const float*)(basec + (((unsigned)ix[6]) << 8) + laneByte);
            a7 += rlane(wk, l + 7) * *(const float*)(basec + (((unsigned)ix[7]) << 8) + laneByte);
        }
    }
    float acc = ((a0 + a1) + (a2 + a3)) + ((a4 + a5) + (a6 + a7));
    return acc * rs;
}

// ---------------------------------------------------------------------------
// Row direction: softmax over sources s for each (h,t); h_ts = elu(attn @ hs).
// grid NT*H/4 blocks, 256 thr. ONE HEAD PER BLOCK; wave w owns row t.
// XCD pinning (empirical xcd = bid%8): head h -> XCDs {2h,2h+1}, so each
// XCD's L2 only sees one 2 MB hs slice (fits 4 MB L2).
// ---------------------------------------------------------------------------
__global__ __launch_bounds__(256) void attn_row_kernel(
    const unsigned long long* __restrict__ mask_row,
    const float* __restrict__ bs, const float* __restrict__ bt,
    const float* __restrict__ hs, float* __restrict__ out_ts) {
    __shared__ __align__(16) unsigned short list[4][ROW_CAP];  // 8 KB

    const int bid = blockIdx.x;
    const int w = threadIdx.x >> 6, lane = threadIdx.x & 63;
    const int h = (bid & 7) >> 1;                        // head -> XCD pair
    const int tgroup = ((bid >> 3) << 1) | (bid & 1);    // [0, NT/4)
    const int t = tgroup * 4 + w;

    const int nnz = wave_compact<NS / 64, ROW_CAP>(
        mask_row, (size_t)t * (NS / 64), list[w], lane);

    const float btv = bt[(size_t)h * NT + t];
    float r = attn_core<ROW_CAP / 64>(list[w], nnz, bs + (size_t)h * NS, btv,
                                      hs + (size_t)h * NS * DOUT, lane);
    out_ts[(size_t)t * (H * DOUT) + h * DOUT + lane] = eluf(r);
}

// ---------------------------------------------------------------------------
// Col direction: softmax over targets t for each (h,s); h_st = elu(attn^T @ ht).
// grid NS*H/4 blocks, 256 thr. One head per block; wave w owns row s.
// ---------------------------------------------------------------------------
__global__ __launch_bounds__(256) void attn_col_kernel(
    const unsigned long long* __restrict__ mask_col,
    const float* __restrict__ bs, const float* __restrict__ bt,
    const float* __restrict__ ht, float* __restrict__ out_st) {
    __shared__ __align__(16) unsigned short list[4][COL_CAP];  // 4 KB

    const int bid = blockIdx.x;
    const int w = threadIdx.x >> 6, lane = threadIdx.x & 63;
    const int h = (bid & 7) >> 1;
    const int sgroup = ((bid >> 3) << 1) | (bid & 1);    // [0, NS/4)
    const int s = sgroup * 4 + w;

    const int nnz = wave_compact<NT / 64, COL_CAP>(
        mask_col, (size_t)s * (NT / 64), list[w], lane);

    const float bsv = bs[(size_t)h * NS + s];
    float r = attn_core<COL_CAP / 64>(list[w], nnz, bt + (size_t)h * NT, bsv,
                                      ht + (size_t)h * NT * DOUT, lane);
    out_st[(size_t)s * (H * DOUT) + h * DOUT + lane] = eluf(r);
}

// ---------------------------------------------------------------------------
extern "C" void kernel_launch(void* const* d_in, const int* in_sizes, int n_in,
                              void* d_out, int out_size, void* d_ws, size_t ws_size,
                              hipStream_t stream) {
    const float* input1 = (const float*)d_in[0];  // [8192,128]
    const float* input2 = (const float*)d_in[1];  // [4096,128]
    const float* A      = (const float*)d_in[2];  // [4096,8192]
    const float* Ws     = (const float*)d_in[3];  // [4,128,64]
    const float* Wt     = (const float*)d_in[4];  // [4,128,64]
    const float* a_src  = (const float*)d_in[5];  // [4,64]
    const float* a_tgt  = (const float*)d_in[6];  // [4,64]
    float* out = (float*)d_out;  // out_st [8192,256] then out_ts [4096,256]

    char* ws = (char*)d_ws;
    float* hs = (float*)(ws + 0);                              // 8 MB   [H,NS,64]
    float* ht = (float*)(ws + 8388608);                        // 4 MB   [H,NT,64]
    float* bs = (float*)(ws + 12582912);                       // 128 KB [H,NS]
    float* bt = (float*)(ws + 12713984);                       // 64 KB  [H,NT]
    unsigned long long* mask_row = (unsigned long long*)(ws + 12779520);  // 4 MB
    unsigned long long* mask_col = (unsigned long long*)(ws + 16973824);  // 4 MB

    proj_kernel<<<dim3(NS / 16, H), 256, 0, stream>>>(input1, Ws, a_src, hs, bs, NS);
    proj_kernel<<<dim3(NT / 16, H), 256, 0, stream>>>(input2, Wt, a_tgt, ht, bt, NT);
    mask_kernel<<<dim3(NS / 64, NT / 64), 256, 0, stream>>>(A, mask_row, mask_col);
    attn_row_kernel<<<NT * H / 4, 256, 0, stream>>>(mask_row, bs, bt, hs,
                                                    out + (size_t)NS * (H * DOUT));
    attn_col_kernel<<<NS * H / 4, 256, 0, stream>>>(mask_col, bs, bt, ht, out);
}

// Round 10
// 417.287 us; speedup vs baseline: 1.1028x; 1.0267x over previous
//
#include <hip/hip_runtime.h>
#include <hip/hip_bf16.h>

#define H 4
#define NS 8192
#define NT 4096
#define DIN 128
#define DOUT 64
#define ROW_CAP 1024   // 16*64 per row
#define COL_CAP 512    // 8*64 per row
#define NEGBIG -3.0e38f

typedef unsigned uint4_vt __attribute__((ext_vector_type(4)));

__device__ __forceinline__ float lrelu(float x) { return x >= 0.f ? x : 0.1f * x; }
__device__ __forceinline__ float eluf(float x) { return x > 0.f ? x : expm1f(x); }

__device__ __forceinline__ float waveMax(float v) {
    for (int off = 32; off > 0; off >>= 1) v = fmaxf(v, __shfl_xor(v, off, 64));
    return v;
}
__device__ __forceinline__ float waveSum(float v) {
    for (int off = 32; off > 0; off >>= 1) v += __shfl_xor(v, off, 64);
    return v;
}
// broadcast lane `l` (compile-time after unroll) of v to all lanes
__device__ __forceinline__ float rlane(float v, int l) {
    return __int_as_float(__builtin_amdgcn_readlane(__float_as_int(v), l));
}

// ---------------------------------------------------------------------------
// Projection: Hout[h,s,o] = sum_i X[s,i] * W[h,i,o];  b[h,s] = Hout[h,s,:]·a[h,:]
// grid (N/16, H), block 256.
// ---------------------------------------------------------------------------
__global__ __launch_bounds__(256) void proj_kernel(
    const float* __restrict__ X, const float* __restrict__ W,
    const float* __restrict__ a_vec, float* __restrict__ Hout,
    float* __restrict__ b_out, int N) {
    __shared__ float w_lds[DIN * DOUT];   // 32 KB
    __shared__ float a_lds[16 * 129];
    const int h = blockIdx.y;
    const int row0 = blockIdx.x * 16;
    const int tid = threadIdx.x;

    const float* Wh = W + (size_t)h * DIN * DOUT;
    for (int i = tid; i < DIN * DOUT; i += 256) w_lds[i] = Wh[i];
    for (int i = tid; i < 16 * DIN; i += 256) {
        int r = i >> 7, c = i & 127;
        a_lds[r * 129 + c] = X[(size_t)(row0 + r) * DIN + c];
    }
    __syncthreads();

    const int fg = (tid & 15) * 4;
    const int r = tid >> 4;
    const float* ar = &a_lds[r * 129];
    float acc0 = 0.f, acc1 = 0.f, acc2 = 0.f, acc3 = 0.f;
#pragma unroll 8
    for (int i = 0; i < DIN; ++i) {
        float av = ar[i];
        float4 wv = *reinterpret_cast<const float4*>(&w_lds[i * DOUT + fg]);
        acc0 += av * wv.x; acc1 += av * wv.y; acc2 += av * wv.z; acc3 += av * wv.w;
    }
    const int s = row0 + r;
    float4 o = make_float4(acc0, acc1, acc2, acc3);
    *reinterpret_cast<float4*>(&Hout[((size_t)h * N + s) * DOUT + fg]) = o;

    const float* av = a_vec + h * DOUT + fg;
    float part = acc0 * av[0] + acc1 * av[1] + acc2 * av[2] + acc3 * av[3];
    for (int off = 8; off > 0; off >>= 1) part += __shfl_xor(part, off, 64);
    if ((tid & 15) == 0) b_out[(size_t)h * N + s] = part;
}

// ---------------------------------------------------------------------------
// Mask build: one HBM pass over dense A -> row-major + col-major bitmasks.
// ---------------------------------------------------------------------------
__global__ __launch_bounds__(256) void mask_kernel(
    const float* __restrict__ A,
    unsigned long long* __restrict__ mask_row,
    unsigned long long* __restrict__ mask_col) {
    __shared__ unsigned long long rowbits[64];
    const int s0 = blockIdx.x * 64;
    const int t0 = blockIdx.y * 64;
    const int lane = threadIdx.x & 63;
    const int w = threadIdx.x >> 6;
    for (int rr = w; rr < 64; rr += 4) {
        const int t = t0 + rr;
        float v = A[(size_t)t * NS + s0 + lane];
        unsigned long long word = __ballot(v != 0.0f);
        if (lane == 0) {
            mask_row[(size_t)t * (NS / 64) + (s0 >> 6)] = word;
            rowbits[rr] = word;
        }
    }
    __syncthreads();
    if (threadIdx.x < 64) {
        const int j = threadIdx.x;
        unsigned long long cw = 0;
        for (int rr = 0; rr < 64; ++rr) cw |= ((rowbits[rr] >> j) & 1ull) << rr;
        mask_col[(size_t)(s0 + j) * (NT / 64) + (t0 >> 6)] = cw;
    }
}

// ---------------------------------------------------------------------------
// Per-WAVE compaction: NWORDS bitmask words -> u32 index list, wave-scan.
// ---------------------------------------------------------------------------
template <int NWORDS, int CAP>
__device__ __forceinline__ int wave_compact(
    const unsigned long long* __restrict__ mask, size_t word_base,
    unsigned* list, int lane) {
    int total = 0;
#pragma unroll
    for (int c = 0; c < NWORDS / 64; ++c) {
        unsigned long long wd = mask[word_base + c * 64 + lane];
        int cnt = __popcll(wd);
        int incl = cnt;
#pragma unroll
        for (int d = 1; d < 64; d <<= 1) {
            int v = __shfl_up(incl, d, 64);
            if (lane >= d) incl += v;
        }
        int off = total + incl - cnt;
        const int base = (c * 64 + lane) * 64;
        while (wd) {
            int b = __ffsll((long long)wd) - 1;
            if (off < CAP) list[off] = (unsigned)(base + b);
            ++off;
            wd &= wd - 1;
        }
        total += __shfl(incl, 63, 64);
    }
    int nnz = total > CAP ? CAP : total;
    int nk64 = (nnz + 63) & ~63;
    for (int j = nnz + lane; j < nk64; j += 64) list[j] = 0;
    return nnz;
}

// ---------------------------------------------------------------------------
// Core per-(h,row) attention. Weights in registers (lane j&63, slot j>>6).
// Gather: u32 idx via broadcast b128 (no extraction), saddr-form loads
// (uniform base + unsigned 32-bit offset), weight via v_readlane.
// ---------------------------------------------------------------------------
template <int KMAX>
__device__ __forceinline__ float attn_core(
    const unsigned* __restrict__ list, int nnz,
    const float* __restrict__ bvec,   // partner bias vector, head slice
    float bias,                       // own bias
    const float* __restrict__ src,    // hs/ht head slice (wave-uniform base)
    int lane) {
    const int nk = (nnz + 63) >> 6;
    float wreg[KMAX];

    // pass 1: gather partner biases, find max
    float m = NEGBIG;
#pragma unroll
    for (int k = 0; k < KMAX; ++k) {
        if (k >= nk) break;
        int j = (k << 6) + lane;
        float p = NEGBIG;
        if (j < nnz) p = bvec[list[j]];
        wreg[k] = p;
        m = fmaxf(m, p);
    }
    m = waveMax(m);
    const float mrow = lrelu(bias + m);   // lrelu monotone => exact max

    // pass 2: weights into registers (0 for pads), sum
    float ssum = 0.f;
#pragma unroll
    for (int k = 0; k < KMAX; ++k) {
        if (k >= nk) break;
        int j = (k << 6) + lane;
        float w = 0.f;
        if (j < nnz) w = __expf(lrelu(bias + wreg[k]) - mrow);
        wreg[k] = w;
        ssum += w;
    }
    ssum = waveSum(ssum);
    const float rs = ssum > 0.f ? 1.0f / ssum : 0.f;

    // gather: per k, 64 edges. 2x b128 broadcast -> 8 u32 idx in VGPRs;
    // per edge: v_lshl_add_u32 (idx<<6 + lane) + saddr load + readlane + fmac.
    const unsigned ulane = (unsigned)lane;
    float a0 = 0.f, a1 = 0.f, a2 = 0.f, a3 = 0.f;
    float a4 = 0.f, a5 = 0.f, a6 = 0.f, a7 = 0.f;
#pragma unroll
    for (int k = 0; k < KMAX; ++k) {
        if (k >= nk) break;
        const float wk = wreg[k];
        const uint4_vt* lp = reinterpret_cast<const uint4_vt*>(&list[k << 6]);
#pragma unroll
        for (int g = 0; g < 16; g += 2) {
            uint4_vt i0 = lp[g];
            uint4_vt i1 = lp[g + 1];
            const int l = g << 2;
            a0 += rlane(wk, l + 0) * src[(i0[0] << 6) + ulane];
            a1 += rlane(wk, l + 1) * src[(i0[1] << 6) + ulane];
            a2 += rlane(wk, l + 2) * src[(i0[2] << 6) + ulane];
            a3 += rlane(wk, l + 3) * src[(i0[3] << 6) + ulane];
            a4 += rlane(wk, l + 4) * src[(i1[0] << 6) + ulane];
            a5 += rlane(wk, l + 5) * src[(i1[1] << 6) + ulane];
            a6 += rlane(wk, l + 6) * src[(i1[2] << 6) + ulane];
            a7 += rlane(wk, l + 7) * src[(i1[3] << 6) + ulane];
        }
    }
    float acc = ((a0 + a1) + (a2 + a3)) + ((a4 + a5) + (a6 + a7));
    return acc * rs;
}

// ---------------------------------------------------------------------------
// Row direction: softmax over sources s for each (h,t); h_ts = elu(attn @ hs).
// grid NT*H/4, block 256. One head per block; wave w owns row t.
// XCD pinning (xcd = bid%8): head h -> XCDs {2h,2h+1} => per-XCD L2 only
// sees one 2 MB hs slice (fits 4 MB). [R8: FETCH 351MB -> 12.6MB]
// ---------------------------------------------------------------------------
__global__ __launch_bounds__(256) void attn_row_kernel(
    const unsigned long long* __restrict__ mask_row,
    const float* __restrict__ bs, const float* __restrict__ bt,
    const float* __restrict__ hs, float* __restrict__ out_ts) {
    __shared__ __align__(16) unsigned list[4][ROW_CAP];  // 16 KB

    const int bid = blockIdx.x;
    const int w = threadIdx.x >> 6, lane = threadIdx.x & 63;
    const int h = (bid & 7) >> 1;                        // head -> XCD pair
    const int tgroup = ((bid >> 3) << 1) | (bid & 1);    // [0, NT/4)
    const int t = tgroup * 4 + w;

    const int nnz = wave_compact<NS / 64, ROW_CAP>(
        mask_row, (size_t)t * (NS / 64), list[w], lane);

    const float btv = bt[(size_t)h * NT + t];
    float r = attn_core<ROW_CAP / 64>(list[w], nnz, bs + (size_t)h * NS, btv,
                                      hs + (size_t)h * NS * DOUT, lane);
    out_ts[(size_t)t * (H * DOUT) + h * DOUT + lane] = eluf(r);
}

// ---------------------------------------------------------------------------
// Col direction: softmax over targets t for each (h,s); h_st = elu(attn^T @ ht).
// grid NS*H/4, block 256. One head per block; wave w owns row s.
// ---------------------------------------------------------------------------
__global__ __launch_bounds__(256) void attn_col_kernel(
    const unsigned long long* __restrict__ mask_col,
    const float* __restrict__ bs, const float* __restrict__ bt,
    const float* __restrict__ ht, float* __restrict__ out_st) {
    __shared__ __align__(16) unsigned list[4][COL_CAP];  // 8 KB

    const int bid = blockIdx.x;
    const int w = threadIdx.x >> 6, lane = threadIdx.x & 63;
    const int h = (bid & 7) >> 1;
    const int sgroup = ((bid >> 3) << 1) | (bid & 1);    // [0, NS/4)
    const int s = sgroup * 4 + w;

    const int nnz = wave_compact<NT / 64, COL_CAP>(
        mask_col, (size_t)s * (NT / 64), list[w], lane);

    const float bsv = bs[(size_t)h * NS + s];
    float r = attn_core<COL_CAP / 64>(list[w], nnz, bt + (size_t)h * NT, bsv,
                                      ht + (size_t)h * NT * DOUT, lane);
    out_st[(size_t)s * (H * DOUT) + h * DOUT + lane] = eluf(r);
}

// ---------------------------------------------------------------------------
extern "C" void kernel_launch(void* const* d_in, const int* in_sizes, int n_in,
                              void* d_out, int out_size, void* d_ws, size_t ws_size,
                              hipStream_t stream) {
    const float* input1 = (const float*)d_in[0];  // [8192,128]
    const float* input2 = (const float*)d_in[1];  // [4096,128]
    const float* A      = (const float*)d_in[2];  // [4096,8192]
    const float* Ws     = (const float*)d_in[3];  // [4,128,64]
    const float* Wt     = (const float*)d_in[4];  // [4,128,64]
    const float* a_src  = (const float*)d_in[5];  // [4,64]
    const float* a_tgt  = (const float*)d_in[6];  // [4,64]
    float* out = (float*)d_out;  // out_st [8192,256] then out_ts [4096,256]

    char* ws = (char*)d_ws;
    float* hs = (float*)(ws + 0);                              // 8 MB   [H,NS,64]
    float* ht = (float*)(ws + 8388608);                        // 4 MB   [H,NT,64]
    float* bs = (float*)(ws + 12582912);                       // 128 KB [H,NS]
    float* bt = (float*)(ws + 12713984);                       // 64 KB  [H,NT]
    unsigned long long* mask_row = (unsigned long long*)(ws + 12779520);  // 4 MB
    unsigned long long* mask_col = (unsigned long long*)(ws + 16973824);  // 4 MB

    proj_kernel<<<dim3(NS / 16, H), 256, 0, stream>>>(input1, Ws, a_src, hs, bs, NS);
    proj_kernel<<<dim3(NT / 16, H), 256, 0, stream>>>(input2, Wt, a_tgt, ht, bt, NT);
    mask_kernel<<<dim3(NS / 64, NT / 64), 256, 0, stream>>>(A, mask_row, mask_col);
    attn_row_kernel<<<NT * H / 4, 256, 0, stream>>>(mask_row, bs, bt, hs,
                                                    out + (size_t)NS * (H * DOUT));
    attn_col_kernel<<<NS * H / 4, 256, 0, stream>>>(mask_col, bs, bt, ht, out);
}

// Round 16
// 410.748 us; speedup vs baseline: 1.1203x; 1.0159x over previous
//
#include <hip/hip_runtime.h>
#include <hip/hip_bf16.h>

#define H 4
#define NS 8192
#define NT 4096
#define DIN 128
#define DOUT 64
#define ROW_CAP 1024   // 16*64 per row
#define COL_CAP 512    // 8*64 per row
#define NEGBIG -3.0e38f

typedef unsigned uint4_vt __attribute__((ext_vector_type(4)));

__device__ __forceinline__ float lrelu(float x) { return x >= 0.f ? x : 0.1f * x; }
__device__ __forceinline__ float eluf(float x) { return x > 0.f ? x : expm1f(x); }

__device__ __forceinline__ float waveMax(float v) {
    for (int off = 32; off > 0; off >>= 1) v = fmaxf(v, __shfl_xor(v, off, 64));
    return v;
}
__device__ __forceinline__ float waveSum(float v) {
    for (int off = 32; off > 0; off >>= 1) v += __shfl_xor(v, off, 64);
    return v;
}
// broadcast lane `l` (compile-time after unroll) of v to all lanes
__device__ __forceinline__ float rlane(float v, int l) {
    return __int_as_float(__builtin_amdgcn_readlane(__float_as_int(v), l));
}

// ---------------------------------------------------------------------------
// Projection: Hout[h,s,o] = sum_i X[s,i] * W[h,i,o];  b[h,s] = Hout[h,s,:]·a[h,:]
// grid (N/16, H), block 256.
// ---------------------------------------------------------------------------
__global__ __launch_bounds__(256) void proj_kernel(
    const float* __restrict__ X, const float* __restrict__ W,
    const float* __restrict__ a_vec, float* __restrict__ Hout,
    float* __restrict__ b_out, int N) {
    __shared__ float w_lds[DIN * DOUT];   // 32 KB
    __shared__ float a_lds[16 * 129];
    const int h = blockIdx.y;
    const int row0 = blockIdx.x * 16;
    const int tid = threadIdx.x;

    const float* Wh = W + (size_t)h * DIN * DOUT;
    for (int i = tid; i < DIN * DOUT; i += 256) w_lds[i] = Wh[i];
    for (int i = tid; i < 16 * DIN; i += 256) {
        int r = i >> 7, c = i & 127;
        a_lds[r * 129 + c] = X[(size_t)(row0 + r) * DIN + c];
    }
    __syncthreads();

    const int fg = (tid & 15) * 4;
    const int r = tid >> 4;
    const float* ar = &a_lds[r * 129];
    float acc0 = 0.f, acc1 = 0.f, acc2 = 0.f, acc3 = 0.f;
#pragma unroll 8
    for (int i = 0; i < DIN; ++i) {
        float av = ar[i];
        float4 wv = *reinterpret_cast<const float4*>(&w_lds[i * DOUT + fg]);
        acc0 += av * wv.x; acc1 += av * wv.y; acc2 += av * wv.z; acc3 += av * wv.w;
    }
    const int s = row0 + r;
    float4 o = make_float4(acc0, acc1, acc2, acc3);
    *reinterpret_cast<float4*>(&Hout[((size_t)h * N + s) * DOUT + fg]) = o;

    const float* av = a_vec + h * DOUT + fg;
    float part = acc0 * av[0] + acc1 * av[1] + acc2 * av[2] + acc3 * av[3];
    for (int off = 8; off > 0; off >>= 1) part += __shfl_xor(part, off, 64);
    if ((tid & 15) == 0) b_out[(size_t)h * N + s] = part;
}

// ---------------------------------------------------------------------------
// Mask build: one HBM pass over dense A -> row-major + col-major bitmasks.
// ---------------------------------------------------------------------------
__global__ __launch_bounds__(256) void mask_kernel(
    const float* __restrict__ A,
    unsigned long long* __restrict__ mask_row,
    unsigned long long* __restrict__ mask_col) {
    __shared__ unsigned long long rowbits[64];
    const int s0 = blockIdx.x * 64;
    const int t0 = blockIdx.y * 64;
    const int lane = threadIdx.x & 63;
    const int w = threadIdx.x >> 6;
    for (int rr = w; rr < 64; rr += 4) {
        const int t = t0 + rr;
        float v = A[(size_t)t * NS + s0 + lane];
        unsigned long long word = __ballot(v != 0.0f);
        if (lane == 0) {
            mask_row[(size_t)t * (NS / 64) + (s0 >> 6)] = word;
            rowbits[rr] = word;
        }
    }
    __syncthreads();
    if (threadIdx.x < 64) {
        const int j = threadIdx.x;
        unsigned long long cw = 0;
        for (int rr = 0; rr < 64; ++rr) cw |= ((rowbits[rr] >> j) & 1ull) << rr;
        mask_col[(size_t)(s0 + j) * (NT / 64) + (t0 >> 6)] = cw;
    }
}

// ---------------------------------------------------------------------------
// Per-WAVE compaction: bitmask words -> list of PRE-SHIFTED byte offsets
// (idx << 8 == idx * DOUT * 4). Enables saddr-form gather loads.
// ---------------------------------------------------------------------------
template <int NWORDS, int CAP>
__device__ __forceinline__ int wave_compact(
    const unsigned long long* __restrict__ mask, size_t word_base,
    unsigned* list, int lane) {
    int total = 0;
#pragma unroll
    for (int c = 0; c < NWORDS / 64; ++c) {
        unsigned long long wd = mask[word_base + c * 64 + lane];
        int cnt = __popcll(wd);
        int incl = cnt;
#pragma unroll
        for (int d = 1; d < 64; d <<= 1) {
            int v = __shfl_up(incl, d, 64);
            if (lane >= d) incl += v;
        }
        int off = total + incl - cnt;
        const unsigned base = (unsigned)(c * 64 + lane) * 64u;
        while (wd) {
            int b = __ffsll((long long)wd) - 1;
            if (off < CAP) list[off] = (base + (unsigned)b) << 8;  // byte offset
            ++off;
            wd &= wd - 1;
        }
        total += __shfl(incl, 63, 64);
    }
    int nnz = total > CAP ? CAP : total;
    int nk64 = (nnz + 63) & ~63;
    for (int j = nnz + lane; j < nk64; j += 64) list[j] = 0;
    return nnz;
}

// ---------------------------------------------------------------------------
// Core per-(h,row) attention. Weights in registers (lane j&63, slot j>>6).
// Gather: list holds byte offsets; address = SGPR base + zext(u32 voffset)
// (saddr form) => per edge: 1 v_add_u32 + 1 v_readlane + 1 v_fmac.
// ---------------------------------------------------------------------------
template <int KMAX>
__device__ __forceinline__ float attn_core(
    const unsigned* __restrict__ list, int nnz,
    const float* __restrict__ bvec,   // partner bias vector, head slice
    float bias,                       // own bias
    const float* __restrict__ src,    // hs/ht head slice (wave-uniform base)
    int lane) {
    const int nk = (nnz + 63) >> 6;
    float wreg[KMAX];

    // pass 1: gather partner biases, find max
    float m = NEGBIG;
#pragma unroll
    for (int k = 0; k < KMAX; ++k) {
        if (k >= nk) break;
        int j = (k << 6) + lane;
        float p = NEGBIG;
        if (j < nnz) p = bvec[list[j] >> 8];
        wreg[k] = p;
        m = fmaxf(m, p);
    }
    m = waveMax(m);
    const float mrow = lrelu(bias + m);   // lrelu monotone => exact max

    // pass 2: weights into registers (0 for pads), sum
    float ssum = 0.f;
#pragma unroll
    for (int k = 0; k < KMAX; ++k) {
        if (k >= nk) break;
        int j = (k << 6) + lane;
        float w = 0.f;
        if (j < nnz) w = __expf(lrelu(bias + wreg[k]) - mrow);
        wreg[k] = w;
        ssum += w;
    }
    ssum = waveSum(ssum);
    const float rs = ssum > 0.f ? 1.0f / ssum : 0.f;

    // gather: per k, 64 edges; 2x b128 broadcast -> 8 ready byte-offsets.
    const char* srcb = (const char*)src;
    const unsigned laneoff = (unsigned)lane << 2;
    float a0 = 0.f, a1 = 0.f, a2 = 0.f, a3 = 0.f;
    float a4 = 0.f, a5 = 0.f, a6 = 0.f, a7 = 0.f;
#pragma unroll
    for (int k = 0; k < KMAX; ++k) {
        if (k >= nk) break;
        const float wk = wreg[k];
        const uint4_vt* lp = reinterpret_cast<const uint4_vt*>(&list[k << 6]);
#pragma unroll
        for (int g = 0; g < 16; g += 2) {
            uint4_vt i0 = lp[g];
            uint4_vt i1 = lp[g + 1];
            const int l = g << 2;
            a0 += rlane(wk, l + 0) * *(const float*)(srcb + (i0[0] + laneoff));
            a1 += rlane(wk, l + 1) * *(const float*)(srcb + (i0[1] + laneoff));
            a2 += rlane(wk, l + 2) * *(const float*)(srcb + (i0[2] + laneoff));
            a3 += rlane(wk, l + 3) * *(const float*)(srcb + (i0[3] + laneoff));
            a4 += rlane(wk, l + 4) * *(const float*)(srcb + (i1[0] + laneoff));
            a5 += rlane(wk, l + 5) * *(const float*)(srcb + (i1[1] + laneoff));
            a6 += rlane(wk, l + 6) * *(const float*)(srcb + (i1[2] + laneoff));
            a7 += rlane(wk, l + 7) * *(const float*)(srcb + (i1[3] + laneoff));
        }
    }
    float acc = ((a0 + a1) + (a2 + a3)) + ((a4 + a5) + (a6 + a7));
    return acc * rs;
}

// ---------------------------------------------------------------------------
// Row direction: softmax over sources s for each (h,t); h_ts = elu(attn @ hs).
// grid NT*H/4, block 256. One head per block; wave w owns row t.
// XCD pinning (xcd = bid%8): head h -> XCDs {2h,2h+1} => per-XCD L2 only
// sees one 2 MB hs slice (fits 4 MB). [R8: FETCH 351MB -> 12.6MB]
// ---------------------------------------------------------------------------
__global__ __launch_bounds__(256) void attn_row_kernel(
    const unsigned long long* __restrict__ mask_row,
    const float* __restrict__ bs, const float* __restrict__ bt,
    const float* __restrict__ hs, float* __restrict__ out_ts) {
    __shared__ __align__(16) unsigned list[4][ROW_CAP];  // 16 KB

    const int bid = blockIdx.x;
    const int w = threadIdx.x >> 6, lane = threadIdx.x & 63;
    const int h = (bid & 7) >> 1;                        // head -> XCD pair
    const int tgroup = ((bid >> 3) << 1) | (bid & 1);    // [0, NT/4)
    const int t = tgroup * 4 + w;

    const int nnz = wave_compact<NS / 64, ROW_CAP>(
        mask_row, (size_t)t * (NS / 64), list[w], lane);

    const float btv = bt[(size_t)h * NT + t];
    float r = attn_core<ROW_CAP / 64>(list[w], nnz, bs + (size_t)h * NS, btv,
                                      hs + (size_t)h * NS * DOUT, lane);
    out_ts[(size_t)t * (H * DOUT) + h * DOUT + lane] = eluf(r);
}

// ---------------------------------------------------------------------------
// Col direction: softmax over targets t for each (h,s); h_st = elu(attn^T @ ht).
// grid NS*H/4, block 256. One head per block; wave w owns row s.
// ---------------------------------------------------------------------------
__global__ __launch_bounds__(256) void attn_col_kernel(
    const unsigned long long* __restrict__ mask_col,
    const float* __restrict__ bs, const float* __restrict__ bt,
    const float* __restrict__ ht, float* __restrict__ out_st) {
    __shared__ __align__(16) unsigned list[4][COL_CAP];  // 8 KB

    const int bid = blockIdx.x;
    const int w = threadIdx.x >> 6, lane = threadIdx.x & 63;
    const int h = (bid & 7) >> 1;
    const int sgroup = ((bid >> 3) << 1) | (bid & 1);    // [0, NS/4)
    const int s = sgroup * 4 + w;

    const int nnz = wave_compact<NT / 64, COL_CAP>(
        mask_col, (size_t)s * (NT / 64), list[w], lane);

    const float bsv = bs[(size_t)h * NS + s];
    float r = attn_core<COL_CAP / 64>(list[w], nnz, bt + (size_t)h * NT, bsv,
                                      ht + (size_t)h * NT * DOUT, lane);
    out_st[(size_t)s * (H * DOUT) + h * DOUT + lane] = eluf(r);
}

// ---------------------------------------------------------------------------
extern "C" void kernel_launch(void* const* d_in, const int* in_sizes, int n_in,
                              void* d_out, int out_size, void* d_ws, size_t ws_size,
                              hipStream_t stream) {
    const float* input1 = (const float*)d_in[0];  // [8192,128]
    const float* input2 = (const float*)d_in[1];  // [4096,128]
    const float* A      = (const float*)d_in[2];  // [4096,8192]
    const float* Ws     = (const float*)d_in[3];  // [4,128,64]
    const float* Wt     = (const float*)d_in[4];  // [4,128,64]
    const float* a_src  = (const float*)d_in[5];  // [4,64]
    const float* a_tgt  = (const float*)d_in[6];  // [4,64]
    float* out = (float*)d_out;  // out_st [8192,256] then out_ts [4096,256]

    char* ws = (char*)d_ws;
    float* hs = (float*)(ws + 0);                              // 8 MB   [H,NS,64]
    float* ht = (float*)(ws + 8388608);                        // 4 MB   [H,NT,64]
    float* bs = (float*)(ws + 12582912);                       // 128 KB [H,NS]
    float* bt = (float*)(ws + 12713984);                       // 64 KB  [H,NT]
    unsigned long long* mask_row = (unsigned long long*)(ws + 12779520);  // 4 MB
    unsigned long long* mask_col = (unsigned long long*)(ws + 16973824);  // 4 MB

    proj_kernel<<<dim3(NS / 16, H), 256, 0, stream>>>(input1, Ws, a_src, hs, bs, NS);
    proj_kernel<<<dim3(NT / 16, H), 256, 0, stream>>>(input2, Wt, a_tgt, ht, bt, NT);
    mask_kernel<<<dim3(NS / 64, NT / 64), 256, 0, stream>>>(A, mask_row, mask_col);
    attn_row_kernel<<<NT * H / 4, 256, 0, stream>>>(mask_row, bs, bt, hs,
                                                    out + (size_t)NS * (H * DOUT));
    attn_col_kernel<<<NS * H / 4, 256, 0, stream>>>(mask_col, bs, bt, ht, out);
}

// Round 17
// 390.481 us; speedup vs baseline: 1.1785x; 1.0519x over previous
//
#include <hip/hip_runtime.h>
#include <hip/hip_bf16.h>

#define H 4
#define NS 8192
#define NT 4096
#define DIN 128
#define DOUT 64
#define ROW_CAP 1024   // 16*64 per row
#define COL_CAP 512    // 8*64 per row
#define NEGBIG -3.0e38f

__device__ __forceinline__ float lrelu(float x) { return x >= 0.f ? x : 0.1f * x; }
__device__ __forceinline__ float eluf(float x) { return x > 0.f ? x : expm1f(x); }

__device__ __forceinline__ float waveMax(float v) {
    for (int off = 32; off > 0; off >>= 1) v = fmaxf(v, __shfl_xor(v, off, 64));
    return v;
}
__device__ __forceinline__ float waveSum(float v) {
    for (int off = 32; off > 0; off >>= 1) v += __shfl_xor(v, off, 64);
    return v;
}

// ---------------------------------------------------------------------------
// Projection: Hout[h,s,o] = sum_i X[s,i] * W[h,i,o];  b[h,s] = Hout[h,s,:]·a[h,:]
// grid (N/16, H), block 256.
// ---------------------------------------------------------------------------
__global__ __launch_bounds__(256) void proj_kernel(
    const float* __restrict__ X, const float* __restrict__ W,
    const float* __restrict__ a_vec, float* __restrict__ Hout,
    float* __restrict__ b_out, int N) {
    __shared__ float w_lds[DIN * DOUT];   // 32 KB
    __shared__ float a_lds[16 * 129];
    const int h = blockIdx.y;
    const int row0 = blockIdx.x * 16;
    const int tid = threadIdx.x;

    const float* Wh = W + (size_t)h * DIN * DOUT;
    for (int i = tid; i < DIN * DOUT; i += 256) w_lds[i] = Wh[i];
    for (int i = tid; i < 16 * DIN; i += 256) {
        int r = i >> 7, c = i & 127;
        a_lds[r * 129 + c] = X[(size_t)(row0 + r) * DIN + c];
    }
    __syncthreads();

    const int fg = (tid & 15) * 4;
    const int r = tid >> 4;
    const float* ar = &a_lds[r * 129];
    float acc0 = 0.f, acc1 = 0.f, acc2 = 0.f, acc3 = 0.f;
#pragma unroll 8
    for (int i = 0; i < DIN; ++i) {
        float av = ar[i];
        float4 wv = *reinterpret_cast<const float4*>(&w_lds[i * DOUT + fg]);
        acc0 += av * wv.x; acc1 += av * wv.y; acc2 += av * wv.z; acc3 += av * wv.w;
    }
    const int s = row0 + r;
    float4 o = make_float4(acc0, acc1, acc2, acc3);
    *reinterpret_cast<float4*>(&Hout[((size_t)h * N + s) * DOUT + fg]) = o;

    const float* av = a_vec + h * DOUT + fg;
    float part = acc0 * av[0] + acc1 * av[1] + acc2 * av[2] + acc3 * av[3];
    for (int off = 8; off > 0; off >>= 1) part += __shfl_xor(part, off, 64);
    if ((tid & 15) == 0) b_out[(size_t)h * N + s] = part;
}

// ---------------------------------------------------------------------------
// Mask build: one HBM pass over dense A -> row-major + col-major bitmasks.
// ---------------------------------------------------------------------------
__global__ __launch_bounds__(256) void mask_kernel(
    const float* __restrict__ A,
    unsigned long long* __restrict__ mask_row,
    unsigned long long* __restrict__ mask_col) {
    __shared__ unsigned long long rowbits[64];
    const int s0 = blockIdx.x * 64;
    const int t0 = blockIdx.y * 64;
    const int lane = threadIdx.x & 63;
    const int w = threadIdx.x >> 6;
    for (int rr = w; rr < 64; rr += 4) {
        const int t = t0 + rr;
        float v = A[(size_t)t * NS + s0 + lane];
        unsigned long long word = __ballot(v != 0.0f);
        if (lane == 0) {
            mask_row[(size_t)t * (NS / 64) + (s0 >> 6)] = word;
            rowbits[rr] = word;
        }
    }
    __syncthreads();
    if (threadIdx.x < 64) {
        const int j = threadIdx.x;
        unsigned long long cw = 0;
        for (int rr = 0; rr < 64; ++rr) cw |= ((rowbits[rr] >> j) & 1ull) << rr;
        mask_col[(size_t)(s0 + j) * (NT / 64) + (t0 >> 6)] = cw;
    }
}

// ---------------------------------------------------------------------------
// Per-WAVE compaction: bitmask words -> list of PRE-SHIFTED byte offsets
// (idx << 8 == idx * DOUT * 4). Enables saddr-form gather loads.
// ---------------------------------------------------------------------------
template <int NWORDS, int CAP>
__device__ __forceinline__ int wave_compact(
    const unsigned long long* __restrict__ mask, size_t word_base,
    unsigned* list, int lane) {
    int total = 0;
#pragma unroll
    for (int c = 0; c < NWORDS / 64; ++c) {
        unsigned long long wd = mask[word_base + c * 64 + lane];
        int cnt = __popcll(wd);
        int incl = cnt;
#pragma unroll
        for (int d = 1; d < 64; d <<= 1) {
            int v = __shfl_up(incl, d, 64);
            if (lane >= d) incl += v;
        }
        int off = total + incl - cnt;
        const unsigned base = (unsigned)(c * 64 + lane) * 64u;
        while (wd) {
            int b = __ffsll((long long)wd) - 1;
            if (off < CAP) list[off] = (base + (unsigned)b) << 8;  // byte offset
            ++off;
            wd &= wd - 1;
        }
        total += __shfl(incl, 63, 64);
    }
    int nnz = total > CAP ? CAP : total;
    int nk64 = (nnz + 63) & ~63;
    for (int j = nnz + lane; j < nk64; j += 64) list[j] = 0;
    return nnz;
}

// ---------------------------------------------------------------------------
// Softmax weights into registers + 4-edge dwordx4 gather.
// Quarter q = lane>>4 owns edge (kk*4+q); lane&15 selects the 16 B feature
// chunk. Per 4 edges: 1 ds_read_b32 + 1 ds_bpermute + 1 add + 1 dwordx4 load
// + 4 fmac. Cross-quarter reduce at the end.
// ---------------------------------------------------------------------------
template <int KMAX>
__device__ __forceinline__ void attn_gather4(
    const unsigned* __restrict__ list, int nnz,
    const float* __restrict__ bvec, float bias,
    const char* __restrict__ srcb, int lane,
    float& rs_out, float4& acc_out) {
    const int nk = (nnz + 63) >> 6;
    float wreg[KMAX];

    // pass 1: partner biases, max
    float m = NEGBIG;
#pragma unroll
    for (int k = 0; k < KMAX; ++k) {
        if (k >= nk) break;
        int j = (k << 6) + lane;
        float p = NEGBIG;
        if (j < nnz) p = bvec[list[j] >> 8];
        wreg[k] = p;
        m = fmaxf(m, p);
    }
    m = waveMax(m);
    const float mrow = lrelu(bias + m);   // lrelu monotone => exact max

    // pass 2: weights (0 for pads), sum
    float ssum = 0.f;
#pragma unroll
    for (int k = 0; k < KMAX; ++k) {
        if (k >= nk) break;
        int j = (k << 6) + lane;
        float w = 0.f;
        if (j < nnz) w = __expf(lrelu(bias + wreg[k]) - mrow);
        wreg[k] = w;
        ssum += w;
    }
    ssum = waveSum(ssum);
    rs_out = ssum > 0.f ? 1.0f / ssum : 0.f;

    // gather
    const int qsel = lane >> 4;                       // quarter 0..3
    const unsigned lane16 = (unsigned)(lane & 15) << 4;
    float4 acc = make_float4(0.f, 0.f, 0.f, 0.f);
#pragma unroll
    for (int k = 0; k < KMAX; ++k) {
        if (k >= nk) break;
        const float wk = wreg[k];
        const unsigned* lk = list + (k << 6);
#pragma unroll 4
        for (int kk = 0; kk < 16; ++kk) {
            const int e = (kk << 2) + qsel;           // edge slot 0..63
            unsigned off = lk[e];                      // ds_read_b32 (broadcast/quarter)
            float w = __shfl(wk, e, 64);               // ds_bpermute
            const float4 v = *reinterpret_cast<const float4*>(srcb + (off + lane16));
            acc.x += w * v.x; acc.y += w * v.y;
            acc.z += w * v.z; acc.w += w * v.w;
        }
    }
#pragma unroll
    for (int mx = 16; mx < 64; mx <<= 1) {
        acc.x += __shfl_xor(acc.x, mx, 64);
        acc.y += __shfl_xor(acc.y, mx, 64);
        acc.z += __shfl_xor(acc.z, mx, 64);
        acc.w += __shfl_xor(acc.w, mx, 64);
    }
    acc_out = acc;
}

// ---------------------------------------------------------------------------
// Fused attention: blocks [0, NT*H/4) do row-softmax (out_ts); blocks
// [NT*H/4, NT*H/4 + NS*H/4) do col-softmax (out_st). One head per block;
// wave w owns one output row. XCD pinning: h = (bid&7)>>1 in both halves
// (offset 4096 ≡ 0 mod 8) => per-XCD L2 sees hs_h (2MB) + ht_h (1MB) < 4MB.
// [R8: FETCH 351MB -> 12.6MB with this pinning]
// ---------------------------------------------------------------------------
__global__ __launch_bounds__(256) void attn_fused_kernel(
    const unsigned long long* __restrict__ mask_row,
    const unsigned long long* __restrict__ mask_col,
    const float* __restrict__ bs, const float* __restrict__ bt,
    const float* __restrict__ hs, const float* __restrict__ ht,
    float* __restrict__ out_st, float* __restrict__ out_ts) {
    __shared__ __align__(16) unsigned list[4][ROW_CAP];  // 16 KB (col uses 8)

    const int bid = blockIdx.x;
    const int w = threadIdx.x >> 6, lane = threadIdx.x & 63;

    if (bid < NT * H / 4) {
        const int h = (bid & 7) >> 1;
        const int tgroup = ((bid >> 3) << 1) | (bid & 1);    // [0, NT/4)
        const int t = tgroup * 4 + w;
        const int nnz = wave_compact<NS / 64, ROW_CAP>(
            mask_row, (size_t)t * (NS / 64), list[w], lane);
        float rs; float4 acc;
        attn_gather4<ROW_CAP / 64>(list[w], nnz, bs + (size_t)h * NS,
                                   bt[(size_t)h * NT + t],
                                   (const char*)(hs + (size_t)h * NS * DOUT),
                                   lane, rs, acc);
        if (lane < 16) {
            float4 o;
            o.x = eluf(acc.x * rs); o.y = eluf(acc.y * rs);
            o.z = eluf(acc.z * rs); o.w = eluf(acc.w * rs);
            *reinterpret_cast<float4*>(
                &out_ts[(size_t)t * (H * DOUT) + h * DOUT + lane * 4]) = o;
        }
    } else {
        const int b2 = bid - NT * H / 4;
        const int h = (b2 & 7) >> 1;
        const int sgroup = ((b2 >> 3) << 1) | (b2 & 1);      // [0, NS/4)
        const int s = sgroup * 4 + w;
        const int nnz = wave_compact<NT / 64, COL_CAP>(
            mask_col, (size_t)s * (NT / 64), list[w], lane);
        float rs; float4 acc;
        attn_gather4<COL_CAP / 64>(list[w], nnz, bt + (size_t)h * NT,
                                   bs[(size_t)h * NS + s],
                                   (const char*)(ht + (size_t)h * NT * DOUT),
                                   lane, rs, acc);
        if (lane < 16) {
            float4 o;
            o.x = eluf(acc.x * rs); o.y = eluf(acc.y * rs);
            o.z = eluf(acc.z * rs); o.w = eluf(acc.w * rs);
            *reinterpret_cast<float4*>(
                &out_st[(size_t)s * (H * DOUT) + h * DOUT + lane * 4]) = o;
        }
    }
}

// ---------------------------------------------------------------------------
extern "C" void kernel_launch(void* const* d_in, const int* in_sizes, int n_in,
                              void* d_out, int out_size, void* d_ws, size_t ws_size,
                              hipStream_t stream) {
    const float* input1 = (const float*)d_in[0];  // [8192,128]
    const float* input2 = (const float*)d_in[1];  // [4096,128]
    const float* A      = (const float*)d_in[2];  // [4096,8192]
    const float* Ws     = (const float*)d_in[3];  // [4,128,64]
    const float* Wt     = (const float*)d_in[4];  // [4,128,64]
    const float* a_src  = (const float*)d_in[5];  // [4,64]
    const float* a_tgt  = (const float*)d_in[6];  // [4,64]
    float* out = (float*)d_out;  // out_st [8192,256] then out_ts [4096,256]

    char* ws = (char*)d_ws;
    float* hs = (float*)(ws + 0);                              // 8 MB   [H,NS,64]
    float* ht = (float*)(ws + 8388608);                        // 4 MB   [H,NT,64]
    float* bs = (float*)(ws + 12582912);                       // 128 KB [H,NS]
    float* bt = (float*)(ws + 12713984);                       // 64 KB  [H,NT]
    unsigned long long* mask_row = (unsigned long long*)(ws + 12779520);  // 4 MB
    unsigned long long* mask_col = (unsigned long long*)(ws + 16973824);  // 4 MB

    proj_kernel<<<dim3(NS / 16, H), 256, 0, stream>>>(input1, Ws, a_src, hs, bs, NS);
    proj_kernel<<<dim3(NT / 16, H), 256, 0, stream>>>(input2, Wt, a_tgt, ht, bt, NT);
    mask_kernel<<<dim3(NS / 64, NT / 64), 256, 0, stream>>>(A, mask_row, mask_col);
    attn_fused_kernel<<<(NT * H + NS * H) / 4, 256, 0, stream>>>(
        mask_row, mask_col, bs, bt, hs, ht,
        out, out + (size_t)NS * (H * DOUT));
}